// Round 1
// baseline (513.898 us; speedup 1.0000x reference)
//
#include <hip/hip_runtime.h>
#include <hip/hip_bf16.h>
#include <stdint.h>

#define B_    4
#define QL_   512
#define KVL_  4096
#define QDIM  1024
#define KVDIM 768
#define NCH   1024
#define H_    8
#define DH    128

typedef unsigned short ushort_t;
typedef __attribute__((ext_vector_type(8))) short bf16x8;
typedef __attribute__((ext_vector_type(4))) float f32x4;
typedef __attribute__((ext_vector_type(4))) unsigned short us4;

__device__ __forceinline__ ushort_t f2bf(float x){
  union { float f; unsigned u; } v; v.f = x;
  unsigned r = v.u + 0x7FFF + ((v.u >> 16) & 1);
  return (ushort_t)(r >> 16);
}

__device__ __forceinline__ void gload16(void* l, const void* g){
  __builtin_amdgcn_global_load_lds(
    (const __attribute__((address_space(1))) unsigned int*)g,
    (__attribute__((address_space(3))) unsigned int*)l, 16, 0, 0);
}

// ---------------- LayerNorm + bf16 cast ----------------
template<int D>
__global__ void ln_kernel(const float* __restrict__ x, const float* __restrict__ gamma,
                          const float* __restrict__ beta, ushort_t* __restrict__ out){
  int row = blockIdx.x;
  const float* xr = x + (size_t)row * D;
  ushort_t* orow = out + (size_t)row * D;
  int tid = threadIdx.x;
  constexpr int NPT = D / 256;
  float v[NPT];
  float s = 0.f, s2 = 0.f;
  #pragma unroll
  for (int k = 0; k < NPT; ++k){ v[k] = xr[tid + k*256]; s += v[k]; s2 += v[k]*v[k]; }
  #pragma unroll
  for (int m = 32; m; m >>= 1){ s += __shfl_xor(s, m); s2 += __shfl_xor(s2, m); }
  __shared__ float red[8];
  int w = tid >> 6;
  if ((tid & 63) == 0){ red[w] = s; red[4 + w] = s2; }
  __syncthreads();
  s  = red[0] + red[1] + red[2] + red[3];
  s2 = red[4] + red[5] + red[6] + red[7];
  float mu  = s / D;
  float var = s2 / D - mu * mu;
  float rs  = rsqrtf(var + 1e-3f);
  #pragma unroll
  for (int k = 0; k < NPT; ++k){
    int i = tid + k*256;
    orow[i] = f2bf((v[k] - mu) * rs * gamma[i] + beta[i]);
  }
}

// ---------------- Weight transpose + bf16 cast: Wt[n][k] = W[k][n] ----------------
__global__ void wtrans_kernel(const float* __restrict__ W, ushort_t* __restrict__ Wt,
                              int K, int N){
  __shared__ float t[32][33];
  int n0 = blockIdx.x * 32, k0 = blockIdx.y * 32;
  int tx = threadIdx.x & 31, ty = threadIdx.x >> 5;   // 32 x 8
  #pragma unroll
  for (int i = 0; i < 32; i += 8) t[ty + i][tx] = W[(size_t)(k0 + ty + i) * N + n0 + tx];
  __syncthreads();
  #pragma unroll
  for (int i = 0; i < 32; i += 8)
    Wt[(size_t)(n0 + ty + i) * K + k0 + tx] = f2bf(t[tx][ty + i]);
}

// ---------------- GEMM: C[m][n] = sum_k A[m][k] * Bw[n][k] + bias[n] ----------------
// A bf16 [M][K], Bw bf16 [N][K] (pre-transposed weight), out bf16.
// TRANSV: scatter into Vt[b][h][dv][kv] layout instead of row-major [M][N].
template<bool TRANSV>
__global__ __launch_bounds__(256)
void gemm_kernel(const ushort_t* __restrict__ A, const ushort_t* __restrict__ Bw,
                 const float* __restrict__ bias, ushort_t* __restrict__ out,
                 int M, int K){
  // fragment-linear LDS: [operand][kgroup g][row 0..127][8 bf16] -> lane-contiguous 16B chunks
  __shared__ __align__(16) ushort_t lds[2][4][128][8];
  int tid = threadIdx.x;
  int w = tid >> 6, lane = tid & 63;
  int m0 = blockIdx.x * 128, n0 = blockIdx.y * 128;
  int wr = w >> 1, wc = w & 1;
  int g = lane >> 4, j = lane & 15;
  f32x4 acc[4][4] = {};
  const int ksteps = K / 32;
  const ushort_t* Aw  = A  + (size_t)(m0 + lane) * K + w * 8;
  const ushort_t* Bww = Bw + (size_t)(n0 + lane) * K + w * 8;
  for (int ks = 0; ks < ksteps; ++ks){
    #pragma unroll
    for (int i = 0; i < 2; ++i){
      gload16(&lds[0][w][i*64][0], Aw  + (size_t)i*64*K + ks*32);
      gload16(&lds[1][w][i*64][0], Bww + (size_t)i*64*K + ks*32);
    }
    __syncthreads();
    bf16x8 af[4], bfr[4];
    #pragma unroll
    for (int mi = 0; mi < 4; ++mi) af[mi]  = *(const bf16x8*)&lds[0][g][wr*64 + mi*16 + j][0];
    #pragma unroll
    for (int ni = 0; ni < 4; ++ni) bfr[ni] = *(const bf16x8*)&lds[1][g][wc*64 + ni*16 + j][0];
    #pragma unroll
    for (int mi = 0; mi < 4; ++mi)
      #pragma unroll
      for (int ni = 0; ni < 4; ++ni)
        acc[mi][ni] = __builtin_amdgcn_mfma_f32_16x16x32_bf16(af[mi], bfr[ni], acc[mi][ni], 0, 0, 0);
    __syncthreads();
  }
  #pragma unroll
  for (int mi = 0; mi < 4; ++mi){
    int row0 = m0 + wr*64 + mi*16 + g*4;   // 4 consecutive rows (regs)
    #pragma unroll
    for (int ni = 0; ni < 4; ++ni){
      int col = n0 + wc*64 + ni*16 + j;
      float bs = bias[col];
      if (!TRANSV){
        #pragma unroll
        for (int r = 0; r < 4; ++r)
          out[(size_t)(row0 + r) * NCH + col] = f2bf(acc[mi][ni][r] + bs);
      } else {
        int bidx = row0 >> 12, kv = row0 & (KVL_ - 1);
        int h = col >> 7, dv = col & 127;
        us4 pk;
        #pragma unroll
        for (int r = 0; r < 4; ++r) pk[r] = f2bf(acc[mi][ni][r] + bs);
        *(us4*)&out[((size_t)(bidx * H_ + h) * DH + dv) * KVL_ + kv] = pk;
      }
    }
  }
}

// ---------------- Flash attention ----------------
// grid = 256: bid = qt*32 + (b*8+h)  (keeps one (b,h)'s blocks on one XCD)
__global__ __launch_bounds__(256)
void attn_kernel(const ushort_t* __restrict__ Q, const ushort_t* __restrict__ Km,
                 const ushort_t* __restrict__ Vt, float* __restrict__ out){
  __shared__ __align__(16) ushort_t plds[4][16][72];  // per-wave P tile, padded stride
  int bid = blockIdx.x;
  int p = bid & 31, qt = bid >> 5;
  int b = p >> 3, h = p & 7;
  int tid = threadIdx.x;
  int w = tid >> 6, lane = tid & 63;
  int g = lane >> 4, j = lane & 15;
  int q0 = qt * 64 + w * 16;

  bf16x8 qf[4];
  const ushort_t* Qb = Q + (size_t)(b * QL_ + q0 + j) * NCH + h * DH + g * 8;
  #pragma unroll
  for (int kb = 0; kb < 4; ++kb) qf[kb] = *(const bf16x8*)(Qb + kb * 32);

  f32x4 ctx[8] = {};
  float m_[4], l_[4];
  #pragma unroll
  for (int r = 0; r < 4; ++r){ m_[r] = -1e30f; l_[r] = 0.f; }

  ushort_t* myp = &plds[w][0][0];
  const ushort_t* Kb = Km + (size_t)(b * KVL_) * NCH + h * DH + g * 8;
  const ushort_t* Vb = Vt + ((size_t)(b * H_ + h) * DH + j) * KVL_ + g * 8;
  const float SC  = 0.08838834764831845f;   // 1/sqrt(128)
  const float L2E = 1.4426950408889634f;

  for (int kv0 = 0; kv0 < KVL_; kv0 += 64){
    f32x4 s[4] = {};
    #pragma unroll
    for (int kf = 0; kf < 4; ++kf){
      const ushort_t* kr = Kb + (size_t)(kv0 + kf * 16 + j) * NCH;
      #pragma unroll
      for (int kb = 0; kb < 4; ++kb)
        s[kf] = __builtin_amdgcn_mfma_f32_16x16x32_bf16(qf[kb], *(const bf16x8*)(kr + kb * 32), s[kf], 0, 0, 0);
    }
    float mx[4], cf[4], rs_[4];
    #pragma unroll
    for (int r = 0; r < 4; ++r){
      s[0][r] *= SC; s[1][r] *= SC; s[2][r] *= SC; s[3][r] *= SC;
      mx[r] = fmaxf(fmaxf(s[0][r], s[1][r]), fmaxf(s[2][r], s[3][r]));
      #pragma unroll
      for (int msk = 1; msk < 16; msk <<= 1) mx[r] = fmaxf(mx[r], __shfl_xor(mx[r], msk));
    }
    #pragma unroll
    for (int r = 0; r < 4; ++r){
      float mn = fmaxf(m_[r], mx[r]);
      cf[r] = exp2f((m_[r] - mn) * L2E);
      m_[r] = mn;
      #pragma unroll
      for (int kf = 0; kf < 4; ++kf) s[kf][r] = exp2f((s[kf][r] - mn) * L2E);
      rs_[r] = s[0][r] + s[1][r] + s[2][r] + s[3][r];
      #pragma unroll
      for (int msk = 1; msk < 16; msk <<= 1) rs_[r] += __shfl_xor(rs_[r], msk);
      l_[r] = l_[r] * cf[r] + rs_[r];
    }
    #pragma unroll
    for (int df = 0; df < 8; ++df)
      #pragma unroll
      for (int r = 0; r < 4; ++r) ctx[df][r] *= cf[r];
    // P -> LDS in [q][key] (transpose to A-operand layout), wave-internal, no barrier
    #pragma unroll
    for (int kf = 0; kf < 4; ++kf)
      #pragma unroll
      for (int r = 0; r < 4; ++r)
        myp[(g * 4 + r) * 72 + kf * 16 + j] = f2bf(s[kf][r]);
    #pragma unroll
    for (int kc = 0; kc < 2; ++kc){
      bf16x8 pa = *(const bf16x8*)&myp[j * 72 + kc * 32 + g * 8];
      #pragma unroll
      for (int df = 0; df < 8; ++df){
        bf16x8 vf = *(const bf16x8*)(Vb + (size_t)(df * 16) * KVL_ + kv0 + kc * 32);
        ctx[df] = __builtin_amdgcn_mfma_f32_16x16x32_bf16(pa, vf, ctx[df], 0, 0, 0);
      }
    }
  }
  float* ob = out + (size_t)(b * QL_ + q0) * NCH + h * DH;
  #pragma unroll
  for (int r = 0; r < 4; ++r){
    float inv = 1.f / l_[r];
    #pragma unroll
    for (int df = 0; df < 8; ++df)
      ob[(size_t)(g * 4 + r) * NCH + df * 16 + j] = ctx[df][r] * inv;
  }
}

extern "C" void kernel_launch(void* const* d_in, const int* in_sizes, int n_in,
                              void* d_out, int out_size, void* d_ws, size_t ws_size,
                              hipStream_t stream){
  const float* hs   = (const float*)d_in[0];
  const float* inp  = (const float*)d_in[1];
  const float* ln1g = (const float*)d_in[2];
  const float* ln1b = (const float*)d_in[3];
  const float* ln2g = (const float*)d_in[4];
  const float* ln2b = (const float*)d_in[5];
  const float* Wq   = (const float*)d_in[6];
  const float* bq   = (const float*)d_in[7];
  const float* Wk   = (const float*)d_in[8];
  const float* bk   = (const float*)d_in[9];
  const float* Wv   = (const float*)d_in[10];
  const float* bv   = (const float*)d_in[11];

  char* ws = (char*)d_ws;
  size_t off = 0;
  auto alloc = [&](size_t bytes){ void* pp = ws + off; off += (bytes + 255) & ~255ull; return pp; };
  ushort_t* hs_ln = (ushort_t*)alloc((size_t)2048 * 1024 * 2);
  ushort_t* in_ln = (ushort_t*)alloc((size_t)16384 * 768 * 2);
  ushort_t* Wqt   = (ushort_t*)alloc((size_t)1024 * 1024 * 2);
  ushort_t* Wkt   = (ushort_t*)alloc((size_t)1024 * 768 * 2);
  ushort_t* Wvt   = (ushort_t*)alloc((size_t)1024 * 768 * 2);
  ushort_t* Qm    = (ushort_t*)alloc((size_t)2048 * 1024 * 2);
  ushort_t* Km    = (ushort_t*)alloc((size_t)16384 * 1024 * 2);
  ushort_t* Vt    = (ushort_t*)alloc((size_t)16384 * 1024 * 2);

  ln_kernel<1024><<<2048, 256, 0, stream>>>(hs, ln1g, ln1b, hs_ln);
  ln_kernel<768><<<16384, 256, 0, stream>>>(inp, ln2g, ln2b, in_ln);
  wtrans_kernel<<<dim3(32, 32), 256, 0, stream>>>(Wq, Wqt, 1024, 1024);
  wtrans_kernel<<<dim3(32, 24), 256, 0, stream>>>(Wk, Wkt, 768, 1024);
  wtrans_kernel<<<dim3(32, 24), 256, 0, stream>>>(Wv, Wvt, 768, 1024);
  gemm_kernel<false><<<dim3(16, 8),  256, 0, stream>>>(hs_ln, Wqt, bq, Qm, 2048, 1024);
  gemm_kernel<false><<<dim3(128, 8), 256, 0, stream>>>(in_ln, Wkt, bk, Km, 16384, 768);
  gemm_kernel<true ><<<dim3(128, 8), 256, 0, stream>>>(in_ln, Wvt, bv, Vt, 16384, 768);
  attn_kernel<<<256, 256, 0, stream>>>(Qm, Km, Vt, (float*)d_out);
}

// Round 2
// 472.129 us; speedup vs baseline: 1.0885x; 1.0885x over previous
//
#include <hip/hip_runtime.h>
#include <hip/hip_bf16.h>
#include <stdint.h>

#define B_    4
#define QL_   512
#define KVL_  4096
#define QDIM  1024
#define KVDIM 768
#define NCH   1024
#define H_    8
#define DH    128
#define NSPLIT 4
#define NROWS (B_ * H_ * QL_)   // 16384 partial rows

typedef unsigned short ushort_t;
typedef __attribute__((ext_vector_type(8))) short bf16x8;
typedef __attribute__((ext_vector_type(4))) float f32x4;
typedef __attribute__((ext_vector_type(4))) unsigned short us4;

__device__ __forceinline__ ushort_t f2bf(float x){
  union { float f; unsigned u; } v; v.f = x;
  unsigned r = v.u + 0x7FFF + ((v.u >> 16) & 1);
  return (ushort_t)(r >> 16);
}

__device__ __forceinline__ void gload16(void* l, const void* g){
  __builtin_amdgcn_global_load_lds(
    (const __attribute__((address_space(1))) unsigned int*)g,
    (__attribute__((address_space(3))) unsigned int*)l, 16, 0, 0);
}

// ---------------- LayerNorm + bf16 cast ----------------
template<int D>
__global__ void ln_kernel(const float* __restrict__ x, const float* __restrict__ gamma,
                          const float* __restrict__ beta, ushort_t* __restrict__ out){
  int row = blockIdx.x;
  const float* xr = x + (size_t)row * D;
  ushort_t* orow = out + (size_t)row * D;
  int tid = threadIdx.x;
  constexpr int NPT = D / 256;
  float v[NPT];
  float s = 0.f, s2 = 0.f;
  #pragma unroll
  for (int k = 0; k < NPT; ++k){ v[k] = xr[tid + k*256]; s += v[k]; s2 += v[k]*v[k]; }
  #pragma unroll
  for (int m = 32; m; m >>= 1){ s += __shfl_xor(s, m); s2 += __shfl_xor(s2, m); }
  __shared__ float red[8];
  int w = tid >> 6;
  if ((tid & 63) == 0){ red[w] = s; red[4 + w] = s2; }
  __syncthreads();
  s  = red[0] + red[1] + red[2] + red[3];
  s2 = red[4] + red[5] + red[6] + red[7];
  float mu  = s / D;
  float var = s2 / D - mu * mu;
  float rs  = rsqrtf(var + 1e-3f);
  #pragma unroll
  for (int k = 0; k < NPT; ++k){
    int i = tid + k*256;
    orow[i] = f2bf((v[k] - mu) * rs * gamma[i] + beta[i]);
  }
}

// ---------------- Weight transpose + bf16 cast: Wt[n][k] = W[k][n] ----------------
__global__ void wtrans_kernel(const float* __restrict__ W, ushort_t* __restrict__ Wt,
                              int K, int N){
  __shared__ float t[32][33];
  int n0 = blockIdx.x * 32, k0 = blockIdx.y * 32;
  int tx = threadIdx.x & 31, ty = threadIdx.x >> 5;   // 32 x 8
  #pragma unroll
  for (int i = 0; i < 32; i += 8) t[ty + i][tx] = W[(size_t)(k0 + ty + i) * N + n0 + tx];
  __syncthreads();
  #pragma unroll
  for (int i = 0; i < 32; i += 8)
    Wt[(size_t)(n0 + ty + i) * K + k0 + tx] = f2bf(t[tx][ty + i]);
}

// ---------------- GEMM: C[m][n] = sum_k A[m][k] * Bw[n][k] + bias[n] ----------------
template<bool TRANSV>
__global__ __launch_bounds__(256)
void gemm_kernel(const ushort_t* __restrict__ A, const ushort_t* __restrict__ Bw,
                 const float* __restrict__ bias, ushort_t* __restrict__ out,
                 int M, int K){
  __shared__ __align__(16) ushort_t lds[2][4][128][8];
  int tid = threadIdx.x;
  int w = tid >> 6, lane = tid & 63;
  int m0 = blockIdx.x * 128, n0 = blockIdx.y * 128;
  int wr = w >> 1, wc = w & 1;
  int g = lane >> 4, j = lane & 15;
  f32x4 acc[4][4] = {};
  const int ksteps = K / 32;
  const ushort_t* Aw  = A  + (size_t)(m0 + lane) * K + w * 8;
  const ushort_t* Bww = Bw + (size_t)(n0 + lane) * K + w * 8;
  for (int ks = 0; ks < ksteps; ++ks){
    #pragma unroll
    for (int i = 0; i < 2; ++i){
      gload16(&lds[0][w][i*64][0], Aw  + (size_t)i*64*K + ks*32);
      gload16(&lds[1][w][i*64][0], Bww + (size_t)i*64*K + ks*32);
    }
    __syncthreads();
    bf16x8 af[4], bfr[4];
    #pragma unroll
    for (int mi = 0; mi < 4; ++mi) af[mi]  = *(const bf16x8*)&lds[0][g][wr*64 + mi*16 + j][0];
    #pragma unroll
    for (int ni = 0; ni < 4; ++ni) bfr[ni] = *(const bf16x8*)&lds[1][g][wc*64 + ni*16 + j][0];
    #pragma unroll
    for (int mi = 0; mi < 4; ++mi)
      #pragma unroll
      for (int ni = 0; ni < 4; ++ni)
        acc[mi][ni] = __builtin_amdgcn_mfma_f32_16x16x32_bf16(af[mi], bfr[ni], acc[mi][ni], 0, 0, 0);
    __syncthreads();
  }
  #pragma unroll
  for (int mi = 0; mi < 4; ++mi){
    int row0 = m0 + wr*64 + mi*16 + g*4;
    #pragma unroll
    for (int ni = 0; ni < 4; ++ni){
      int col = n0 + wc*64 + ni*16 + j;
      float bs = bias[col];
      if (!TRANSV){
        #pragma unroll
        for (int r = 0; r < 4; ++r)
          out[(size_t)(row0 + r) * NCH + col] = f2bf(acc[mi][ni][r] + bs);
      } else {
        int bidx = row0 >> 12, kv = row0 & (KVL_ - 1);
        int h = col >> 7, dv = col & 127;
        us4 pk;
        #pragma unroll
        for (int r = 0; r < 4; ++r) pk[r] = f2bf(acc[mi][ni][r] + bs);
        *(us4*)&out[((size_t)(bidx * H_ + h) * DH + dv) * KVL_ + kv] = pk;
      }
    }
  }
}

// ---------------- Flash attention (KV-split partials) ----------------
// bid: qt = bid&7, bh = (bid>>3)&31, split = bid>>8.  grid = 8*32*NSPLIT = 1024
__global__ __launch_bounds__(256)
void attn_kernel(const ushort_t* __restrict__ Q, const ushort_t* __restrict__ Km,
                 const ushort_t* __restrict__ Vt, float* __restrict__ ctxp,
                 float* __restrict__ mlp){
  __shared__ __align__(16) ushort_t plds[4][16][72];
  int bid = blockIdx.x;
  int qt = bid & 7;
  int p  = (bid >> 3) & 31;
  int sp = bid >> 8;
  int b = p >> 3, h = p & 7;
  int tid = threadIdx.x;
  int w = tid >> 6, lane = tid & 63;
  int g = lane >> 4, j = lane & 15;
  int q0 = qt * 64 + w * 16;

  bf16x8 qf[4];
  const ushort_t* Qb = Q + (size_t)(b * QL_ + q0 + j) * NCH + h * DH + g * 8;
  #pragma unroll
  for (int kb = 0; kb < 4; ++kb) qf[kb] = *(const bf16x8*)(Qb + kb * 32);

  f32x4 ctx[8] = {};
  float m_[4], l_[4];
  #pragma unroll
  for (int r = 0; r < 4; ++r){ m_[r] = -1e30f; l_[r] = 0.f; }

  ushort_t* myp = &plds[w][0][0];
  const ushort_t* Kb = Km + (size_t)(b * KVL_) * NCH + h * DH + g * 8;
  const ushort_t* Vb = Vt + ((size_t)(b * H_ + h) * DH + j) * KVL_ + g * 8;
  const float SC  = 0.08838834764831845f;   // 1/sqrt(128)
  const float L2E = 1.4426950408889634f;

  const int kvbeg = sp * (KVL_ / NSPLIT);
  const int kvend = kvbeg + (KVL_ / NSPLIT);
  for (int kv0 = kvbeg; kv0 < kvend; kv0 += 64){
    f32x4 s[4] = {};
    #pragma unroll
    for (int kf = 0; kf < 4; ++kf){
      const ushort_t* kr = Kb + (size_t)(kv0 + kf * 16 + j) * NCH;
      #pragma unroll
      for (int kb = 0; kb < 4; ++kb)
        s[kf] = __builtin_amdgcn_mfma_f32_16x16x32_bf16(qf[kb], *(const bf16x8*)(kr + kb * 32), s[kf], 0, 0, 0);
    }
    float mx[4], cf[4], rs_[4];
    #pragma unroll
    for (int r = 0; r < 4; ++r){
      s[0][r] *= SC; s[1][r] *= SC; s[2][r] *= SC; s[3][r] *= SC;
      mx[r] = fmaxf(fmaxf(s[0][r], s[1][r]), fmaxf(s[2][r], s[3][r]));
      #pragma unroll
      for (int msk = 1; msk < 16; msk <<= 1) mx[r] = fmaxf(mx[r], __shfl_xor(mx[r], msk));
    }
    #pragma unroll
    for (int r = 0; r < 4; ++r){
      float mn = fmaxf(m_[r], mx[r]);
      cf[r] = exp2f((m_[r] - mn) * L2E);
      m_[r] = mn;
      #pragma unroll
      for (int kf = 0; kf < 4; ++kf) s[kf][r] = exp2f((s[kf][r] - mn) * L2E);
      rs_[r] = s[0][r] + s[1][r] + s[2][r] + s[3][r];
      #pragma unroll
      for (int msk = 1; msk < 16; msk <<= 1) rs_[r] += __shfl_xor(rs_[r], msk);
      l_[r] = l_[r] * cf[r] + rs_[r];
    }
    #pragma unroll
    for (int df = 0; df < 8; ++df)
      #pragma unroll
      for (int r = 0; r < 4; ++r) ctx[df][r] *= cf[r];
    #pragma unroll
    for (int kf = 0; kf < 4; ++kf)
      #pragma unroll
      for (int r = 0; r < 4; ++r)
        myp[(g * 4 + r) * 72 + kf * 16 + j] = f2bf(s[kf][r]);
    #pragma unroll
    for (int kc = 0; kc < 2; ++kc){
      bf16x8 pa = *(const bf16x8*)&myp[j * 72 + kc * 32 + g * 8];
      #pragma unroll
      for (int df = 0; df < 8; ++df){
        bf16x8 vf = *(const bf16x8*)(Vb + (size_t)(df * 16) * KVL_ + kv0 + kc * 32);
        ctx[df] = __builtin_amdgcn_mfma_f32_16x16x32_bf16(pa, vf, ctx[df], 0, 0, 0);
      }
    }
  }
  // write unnormalized partials
  size_t prow0 = ((size_t)sp * 32 + b * 8 + h) * QL_ + q0;
  #pragma unroll
  for (int r = 0; r < 4; ++r){
    float* cp = ctxp + (prow0 + g * 4 + r) * DH;
    #pragma unroll
    for (int df = 0; df < 8; ++df) cp[df * 16 + j] = ctx[df][r];
  }
  if (j == 0){
    #pragma unroll
    for (int r = 0; r < 4; ++r){
      size_t pr = prow0 + g * 4 + r;
      mlp[pr * 2]     = m_[r];
      mlp[pr * 2 + 1] = l_[r];
    }
  }
}

// ---------------- Split combine: 1 wave per q-row ----------------
__global__ __launch_bounds__(256)
void combine_kernel(const float* __restrict__ ctxp, const float* __restrict__ mlp,
                    float* __restrict__ out){
  int row = blockIdx.x * 4 + (threadIdx.x >> 6);   // (b*8+h)*512 + q, row < 16384
  int lane = threadIdx.x & 63;
  int b = row >> 12, h = (row >> 9) & 7, q = row & 511;
  float ms[NSPLIT], ls[NSPLIT];
  #pragma unroll
  for (int s = 0; s < NSPLIT; ++s){
    ms[s] = mlp[((size_t)(s * NROWS + row)) * 2];
    ls[s] = mlp[((size_t)(s * NROWS + row)) * 2 + 1];
  }
  float M = fmaxf(fmaxf(ms[0], ms[1]), fmaxf(ms[2], ms[3]));
  float wgt[NSPLIT], L = 0.f;
  #pragma unroll
  for (int s = 0; s < NSPLIT; ++s){ wgt[s] = expf(ms[s] - M); L += ls[s] * wgt[s]; }
  float inv = 1.f / L;
  float ax = 0.f, ay = 0.f;
  #pragma unroll
  for (int s = 0; s < NSPLIT; ++s){
    const float* cp = ctxp + ((size_t)(s * NROWS + row)) * DH + lane * 2;
    ax += cp[0] * wgt[s]; ay += cp[1] * wgt[s];
  }
  float* op = out + ((size_t)(b * QL_ + q)) * NCH + h * DH + lane * 2;
  op[0] = ax * inv; op[1] = ay * inv;
}

extern "C" void kernel_launch(void* const* d_in, const int* in_sizes, int n_in,
                              void* d_out, int out_size, void* d_ws, size_t ws_size,
                              hipStream_t stream){
  const float* hs   = (const float*)d_in[0];
  const float* inp  = (const float*)d_in[1];
  const float* ln1g = (const float*)d_in[2];
  const float* ln1b = (const float*)d_in[3];
  const float* ln2g = (const float*)d_in[4];
  const float* ln2b = (const float*)d_in[5];
  const float* Wq   = (const float*)d_in[6];
  const float* bq   = (const float*)d_in[7];
  const float* Wk   = (const float*)d_in[8];
  const float* bk   = (const float*)d_in[9];
  const float* Wv   = (const float*)d_in[10];
  const float* bv   = (const float*)d_in[11];

  char* ws = (char*)d_ws;
  size_t off = 0;
  auto alloc = [&](size_t bytes){ void* pp = ws + off; off += (bytes + 255) & ~255ull; return pp; };
  // persistent across phases
  ushort_t* Qm = (ushort_t*)alloc((size_t)2048 * 1024 * 2);
  ushort_t* Km = (ushort_t*)alloc((size_t)16384 * 1024 * 2);
  ushort_t* Vt = (ushort_t*)alloc((size_t)16384 * 1024 * 2);
  size_t base2 = off;
  // phase 1: LN outputs + transposed weights (dead after the GEMMs)
  ushort_t* hs_ln = (ushort_t*)alloc((size_t)2048 * 1024 * 2);
  ushort_t* in_ln = (ushort_t*)alloc((size_t)16384 * 768 * 2);
  ushort_t* Wqt   = (ushort_t*)alloc((size_t)1024 * 1024 * 2);
  ushort_t* Wkt   = (ushort_t*)alloc((size_t)1024 * 768 * 2);
  ushort_t* Wvt   = (ushort_t*)alloc((size_t)1024 * 768 * 2);
  // phase 2: attention partials (alias phase 1)
  off = base2;
  float* ctxp = (float*)alloc((size_t)NSPLIT * NROWS * DH * 4);
  float* mlp  = (float*)alloc((size_t)NSPLIT * NROWS * 2 * 4);

  ln_kernel<1024><<<2048, 256, 0, stream>>>(hs, ln1g, ln1b, hs_ln);
  ln_kernel<768><<<16384, 256, 0, stream>>>(inp, ln2g, ln2b, in_ln);
  wtrans_kernel<<<dim3(32, 32), 256, 0, stream>>>(Wq, Wqt, 1024, 1024);
  wtrans_kernel<<<dim3(32, 24), 256, 0, stream>>>(Wk, Wkt, 768, 1024);
  wtrans_kernel<<<dim3(32, 24), 256, 0, stream>>>(Wv, Wvt, 768, 1024);
  gemm_kernel<false><<<dim3(16, 8),  256, 0, stream>>>(hs_ln, Wqt, bq, Qm, 2048, 1024);
  gemm_kernel<false><<<dim3(128, 8), 256, 0, stream>>>(in_ln, Wkt, bk, Km, 16384, 768);
  gemm_kernel<true ><<<dim3(128, 8), 256, 0, stream>>>(in_ln, Wvt, bv, Vt, 16384, 768);
  attn_kernel<<<8 * 32 * NSPLIT, 256, 0, stream>>>(Qm, Km, Vt, ctxp, mlp);
  combine_kernel<<<NROWS / 4, 256, 0, stream>>>(ctxp, mlp, (float*)d_out);
}

// Round 3
// 285.341 us; speedup vs baseline: 1.8010x; 1.6546x over previous
//
#include <hip/hip_runtime.h>
#include <hip/hip_bf16.h>
#include <stdint.h>

#define B_    4
#define QL_   512
#define KVL_  4096
#define QDIM  1024
#define KVDIM 768
#define NCH   1024
#define H_    8
#define DH    128
#define NSPLIT 4
#define NROWS (B_ * H_ * QL_)   // 16384 partial rows
#define KVBLK 64

typedef unsigned short ushort_t;
typedef __attribute__((ext_vector_type(8))) short bf16x8;
typedef __attribute__((ext_vector_type(4))) float f32x4;
typedef __attribute__((ext_vector_type(4))) unsigned short us4;

__device__ __forceinline__ ushort_t f2bf(float x){
  union { float f; unsigned u; } v; v.f = x;
  unsigned r = v.u + 0x7FFF + ((v.u >> 16) & 1);
  return (ushort_t)(r >> 16);
}

__device__ __forceinline__ void gload16(void* l, const void* g){
  __builtin_amdgcn_global_load_lds(
    (const __attribute__((address_space(1))) unsigned int*)g,
    (__attribute__((address_space(3))) unsigned int*)l, 16, 0, 0);
}

// ---------------- LayerNorm + bf16 cast ----------------
template<int D>
__global__ void ln_kernel(const float* __restrict__ x, const float* __restrict__ gamma,
                          const float* __restrict__ beta, ushort_t* __restrict__ out){
  int row = blockIdx.x;
  const float* xr = x + (size_t)row * D;
  ushort_t* orow = out + (size_t)row * D;
  int tid = threadIdx.x;
  constexpr int NPT = D / 256;
  float v[NPT];
  float s = 0.f, s2 = 0.f;
  #pragma unroll
  for (int k = 0; k < NPT; ++k){ v[k] = xr[tid + k*256]; s += v[k]; s2 += v[k]*v[k]; }
  #pragma unroll
  for (int m = 32; m; m >>= 1){ s += __shfl_xor(s, m); s2 += __shfl_xor(s2, m); }
  __shared__ float red[8];
  int w = tid >> 6;
  if ((tid & 63) == 0){ red[w] = s; red[4 + w] = s2; }
  __syncthreads();
  s  = red[0] + red[1] + red[2] + red[3];
  s2 = red[4] + red[5] + red[6] + red[7];
  float mu  = s / D;
  float var = s2 / D - mu * mu;
  float rs  = rsqrtf(var + 1e-3f);
  #pragma unroll
  for (int k = 0; k < NPT; ++k){
    int i = tid + k*256;
    orow[i] = f2bf((v[k] - mu) * rs * gamma[i] + beta[i]);
  }
}

// ---------------- Weight transpose + bf16 cast: Wt[n][k] = W[k][n] ----------------
__global__ void wtrans_kernel(const float* __restrict__ W, ushort_t* __restrict__ Wt,
                              int K, int N){
  __shared__ float t[32][33];
  int n0 = blockIdx.x * 32, k0 = blockIdx.y * 32;
  int tx = threadIdx.x & 31, ty = threadIdx.x >> 5;   // 32 x 8
  #pragma unroll
  for (int i = 0; i < 32; i += 8) t[ty + i][tx] = W[(size_t)(k0 + ty + i) * N + n0 + tx];
  __syncthreads();
  #pragma unroll
  for (int i = 0; i < 32; i += 8)
    Wt[(size_t)(n0 + ty + i) * K + k0 + tx] = f2bf(t[tx][ty + i]);
}

// ---------------- GEMM: C[m][n] = sum_k A[m][k] * Bw[n][k] + bias[n] ----------------
template<bool TRANSV>
__global__ __launch_bounds__(256)
void gemm_kernel(const ushort_t* __restrict__ A, const ushort_t* __restrict__ Bw,
                 const float* __restrict__ bias, ushort_t* __restrict__ out,
                 int M, int K){
  __shared__ __align__(16) ushort_t lds[2][4][128][8];
  int tid = threadIdx.x;
  int w = tid >> 6, lane = tid & 63;
  int m0 = blockIdx.x * 128, n0 = blockIdx.y * 128;
  int wr = w >> 1, wc = w & 1;
  int g = lane >> 4, j = lane & 15;
  f32x4 acc[4][4] = {};
  const int ksteps = K / 32;
  const ushort_t* Aw  = A  + (size_t)(m0 + lane) * K + w * 8;
  const ushort_t* Bww = Bw + (size_t)(n0 + lane) * K + w * 8;
  for (int ks = 0; ks < ksteps; ++ks){
    #pragma unroll
    for (int i = 0; i < 2; ++i){
      gload16(&lds[0][w][i*64][0], Aw  + (size_t)i*64*K + ks*32);
      gload16(&lds[1][w][i*64][0], Bww + (size_t)i*64*K + ks*32);
    }
    __syncthreads();
    bf16x8 af[4], bfr[4];
    #pragma unroll
    for (int mi = 0; mi < 4; ++mi) af[mi]  = *(const bf16x8*)&lds[0][g][wr*64 + mi*16 + j][0];
    #pragma unroll
    for (int ni = 0; ni < 4; ++ni) bfr[ni] = *(const bf16x8*)&lds[1][g][wc*64 + ni*16 + j][0];
    #pragma unroll
    for (int mi = 0; mi < 4; ++mi)
      #pragma unroll
      for (int ni = 0; ni < 4; ++ni)
        acc[mi][ni] = __builtin_amdgcn_mfma_f32_16x16x32_bf16(af[mi], bfr[ni], acc[mi][ni], 0, 0, 0);
    __syncthreads();
  }
  #pragma unroll
  for (int mi = 0; mi < 4; ++mi){
    int row0 = m0 + wr*64 + mi*16 + g*4;
    #pragma unroll
    for (int ni = 0; ni < 4; ++ni){
      int col = n0 + wc*64 + ni*16 + j;
      float bs = bias[col];
      if (!TRANSV){
        #pragma unroll
        for (int r = 0; r < 4; ++r)
          out[(size_t)(row0 + r) * NCH + col] = f2bf(acc[mi][ni][r] + bs);
      } else {
        int bidx = row0 >> 12, kv = row0 & (KVL_ - 1);
        int h = col >> 7, dv = col & 127;
        us4 pk;
        #pragma unroll
        for (int r = 0; r < 4; ++r) pk[r] = f2bf(acc[mi][ni][r] + bs);
        *(us4*)&out[((size_t)(bidx * H_ + h) * DH + dv) * KVL_ + kv] = pk;
      }
    }
  }
}

// ---------------- Flash attention: 8-wave block, LDS-staged K/V, KV-split ----------------
// grid = 256. bid = xcd + 8*slot; pair p = xcd + 8*(slot>>1) shares (bh,sp) slice; qb = slot&1.
__global__ __launch_bounds__(512, 2)
void attn_kernel(const ushort_t* __restrict__ Q, const ushort_t* __restrict__ Km,
                 const ushort_t* __restrict__ Vt, float* __restrict__ ctxp,
                 float* __restrict__ mlp){
  __shared__ __align__(16) ushort_t Kbuf[2][KVBLK][DH];   // 32 KB
  __shared__ __align__(16) ushort_t Vbuf[2][DH][KVBLK];   // 32 KB
  __shared__ __align__(16) ushort_t plds[8][16][72];      // 18 KB per-wave P tiles

  int bid = blockIdx.x;
  int xcd = bid & 7, slot = bid >> 3;
  int p   = xcd + 8 * (slot >> 1);
  int qb  = slot & 1;
  int bh  = p >> 2, sp = p & 3;
  int b = bh >> 3, h = bh & 7;

  int tid = threadIdx.x;
  int w = tid >> 6, lane = tid & 63;
  int g = lane >> 4, j = lane & 15;
  int qbase = qb * 256 + w * 32;          // wave's 32 q-rows

  // Q fragments: qreg[qf][kb], lane j = q row, k = kb*32 + g*8 + e
  bf16x8 qreg[2][4];
  #pragma unroll
  for (int qf = 0; qf < 2; ++qf){
    const ushort_t* Qb = Q + (size_t)(b * QL_ + qbase + qf * 16 + j) * NCH + h * DH + g * 8;
    #pragma unroll
    for (int kb = 0; kb < 4; ++kb) qreg[qf][kb] = *(const bf16x8*)(Qb + kb * 32);
  }

  f32x4 ctx[2][8] = {};
  float m_[2][4], l_[2][4];
  #pragma unroll
  for (int qf = 0; qf < 2; ++qf)
    #pragma unroll
    for (int r = 0; r < 4; ++r){ m_[qf][r] = -1e30f; l_[qf][r] = 0.f; }

  const int kvbeg = sp * (KVL_ / NSPLIT);
  const char* Kg = (const char*)(Km + (size_t)b * KVL_ * NCH) + h * 256;
  const char* Vg = (const char*)(Vt + (size_t)(b * H_ + h) * DH * KVL_);

  // stage chunk at kv0 into buffer bi (linear dest, inverse-swizzled source)
  auto stage = [&](int bi, int kv0){
    #pragma unroll
    for (int i = 0; i < 2; ++i){
      int lin = (i * 512 + tid) * 16;
      int sw  = lin ^ (((lin >> 8) & 7) << 4);
      gload16((char*)&Kbuf[bi][0][0] + lin,
              Kg + (size_t)(kv0 + (sw >> 8)) * 2048 + (sw & 255));
    }
    #pragma unroll
    for (int i = 0; i < 2; ++i){
      int lin = (i * 512 + tid) * 16;
      int sw  = lin ^ (((lin >> 7) & 7) << 4);
      gload16((char*)&Vbuf[bi][0][0] + lin,
              Vg + (size_t)(sw >> 7) * (KVL_ * 2) + kv0 * 2 + (sw & 127));
    }
  };

  ushort_t* myp = &plds[w][0][0];
  const float SC  = 0.08838834764831845f;   // 1/sqrt(128)
  const float L2E = 1.4426950408889634f;
  const int NCHUNK = (KVL_ / NSPLIT) / KVBLK;   // 16

  stage(0, kvbeg);
  __syncthreads();

  for (int c = 0; c < NCHUNK; ++c){
    int bi = c & 1;
    if (c + 1 < NCHUNK) stage(bi ^ 1, kvbeg + (c + 1) * KVBLK);

    const char* Kl = (const char*)&Kbuf[bi][0][0];
    const char* Vl = (const char*)&Vbuf[bi][0][0];
    bf16x8 pa[2][2];

    #pragma unroll
    for (int qf = 0; qf < 2; ++qf){
      f32x4 s[4] = {};
      #pragma unroll
      for (int kf = 0; kf < 4; ++kf){
        #pragma unroll
        for (int kb = 0; kb < 4; ++kb){
          int off = (kf * 16 + j) * 256 + kb * 64 + g * 16;
          off ^= ((j & 7) << 4);
          s[kf] = __builtin_amdgcn_mfma_f32_16x16x32_bf16(
                    qreg[qf][kb], *(const bf16x8*)(Kl + off), s[kf], 0, 0, 0);
        }
      }
      // online softmax for this q-fragment (rows 4g+r, cols over j)
      float mx[4], cf[4];
      #pragma unroll
      for (int r = 0; r < 4; ++r){
        s[0][r] *= SC; s[1][r] *= SC; s[2][r] *= SC; s[3][r] *= SC;
        mx[r] = fmaxf(fmaxf(s[0][r], s[1][r]), fmaxf(s[2][r], s[3][r]));
        #pragma unroll
        for (int msk = 1; msk < 16; msk <<= 1) mx[r] = fmaxf(mx[r], __shfl_xor(mx[r], msk));
        float mn = fmaxf(m_[qf][r], mx[r]);
        cf[r] = exp2f((m_[qf][r] - mn) * L2E);
        m_[qf][r] = mn;
        float rs_ = 0.f;
        #pragma unroll
        for (int kf = 0; kf < 4; ++kf){ s[kf][r] = exp2f((s[kf][r] - mn) * L2E); rs_ += s[kf][r]; }
        #pragma unroll
        for (int msk = 1; msk < 16; msk <<= 1) rs_ += __shfl_xor(rs_, msk);
        l_[qf][r] = l_[qf][r] * cf[r] + rs_;
      }
      #pragma unroll
      for (int df = 0; df < 8; ++df)
        #pragma unroll
        for (int r = 0; r < 4; ++r) ctx[qf][df][r] *= cf[r];
      // P -> per-wave LDS tile (transpose to A-operand layout)
      #pragma unroll
      for (int kf = 0; kf < 4; ++kf)
        #pragma unroll
        for (int r = 0; r < 4; ++r)
          myp[(g * 4 + r) * 72 + kf * 16 + j] = f2bf(s[kf][r]);
      pa[qf][0] = *(const bf16x8*)&myp[j * 72 + g * 8];
      pa[qf][1] = *(const bf16x8*)&myp[j * 72 + 32 + g * 8];
    }

    // PV: ctx[qf][df] += P * V  (V B-frag from swizzled LDS)
    #pragma unroll
    for (int df = 0; df < 8; ++df){
      #pragma unroll
      for (int kc = 0; kc < 2; ++kc){
        int off = (df * 16 + j) * 128 + kc * 64 + g * 16;
        off ^= ((j & 7) << 4);
        bf16x8 vf = *(const bf16x8*)(Vl + off);
        ctx[0][df] = __builtin_amdgcn_mfma_f32_16x16x32_bf16(pa[0][kc], vf, ctx[0][df], 0, 0, 0);
        ctx[1][df] = __builtin_amdgcn_mfma_f32_16x16x32_bf16(pa[1][kc], vf, ctx[1][df], 0, 0, 0);
      }
    }
    __syncthreads();
  }

  // write unnormalized partials
  size_t prow0 = ((size_t)sp * 32 + bh) * QL_ + qbase;
  #pragma unroll
  for (int qf = 0; qf < 2; ++qf){
    #pragma unroll
    for (int r = 0; r < 4; ++r){
      float* cp = ctxp + (prow0 + qf * 16 + g * 4 + r) * DH;
      #pragma unroll
      for (int df = 0; df < 8; ++df) cp[df * 16 + j] = ctx[qf][df][r];
    }
    if (j == 0){
      #pragma unroll
      for (int r = 0; r < 4; ++r){
        size_t pr = prow0 + qf * 16 + g * 4 + r;
        mlp[pr * 2]     = m_[qf][r];
        mlp[pr * 2 + 1] = l_[qf][r];
      }
    }
  }
}

// ---------------- Split combine: 1 wave per q-row ----------------
__global__ __launch_bounds__(256)
void combine_kernel(const float* __restrict__ ctxp, const float* __restrict__ mlp,
                    float* __restrict__ out){
  int row = blockIdx.x * 4 + (threadIdx.x >> 6);   // (b*8+h)*512 + q, row < 16384
  int lane = threadIdx.x & 63;
  int b = row >> 12, h = (row >> 9) & 7, q = row & 511;
  float ms[NSPLIT], ls[NSPLIT];
  #pragma unroll
  for (int s = 0; s < NSPLIT; ++s){
    ms[s] = mlp[((size_t)(s * NROWS + row)) * 2];
    ls[s] = mlp[((size_t)(s * NROWS + row)) * 2 + 1];
  }
  float M = fmaxf(fmaxf(ms[0], ms[1]), fmaxf(ms[2], ms[3]));
  float wgt[NSPLIT], L = 0.f;
  #pragma unroll
  for (int s = 0; s < NSPLIT; ++s){ wgt[s] = expf(ms[s] - M); L += ls[s] * wgt[s]; }
  float inv = 1.f / L;
  float ax = 0.f, ay = 0.f;
  #pragma unroll
  for (int s = 0; s < NSPLIT; ++s){
    const float* cp = ctxp + ((size_t)(s * NROWS + row)) * DH + lane * 2;
    ax += cp[0] * wgt[s]; ay += cp[1] * wgt[s];
  }
  float* op = out + ((size_t)(b * QL_ + q)) * NCH + h * DH + lane * 2;
  op[0] = ax * inv; op[1] = ay * inv;
}

extern "C" void kernel_launch(void* const* d_in, const int* in_sizes, int n_in,
                              void* d_out, int out_size, void* d_ws, size_t ws_size,
                              hipStream_t stream){
  const float* hs   = (const float*)d_in[0];
  const float* inp  = (const float*)d_in[1];
  const float* ln1g = (const float*)d_in[2];
  const float* ln1b = (const float*)d_in[3];
  const float* ln2g = (const float*)d_in[4];
  const float* ln2b = (const float*)d_in[5];
  const float* Wq   = (const float*)d_in[6];
  const float* bq   = (const float*)d_in[7];
  const float* Wk   = (const float*)d_in[8];
  const float* bk   = (const float*)d_in[9];
  const float* Wv   = (const float*)d_in[10];
  const float* bv   = (const float*)d_in[11];

  char* ws = (char*)d_ws;
  size_t off = 0;
  auto alloc = [&](size_t bytes){ void* pp = ws + off; off += (bytes + 255) & ~255ull; return pp; };
  // persistent across phases
  ushort_t* Qm = (ushort_t*)alloc((size_t)2048 * 1024 * 2);
  ushort_t* Km = (ushort_t*)alloc((size_t)16384 * 1024 * 2);
  ushort_t* Vt = (ushort_t*)alloc((size_t)16384 * 1024 * 2);
  size_t base2 = off;
  // phase 1: LN outputs + transposed weights (dead after the GEMMs)
  ushort_t* hs_ln = (ushort_t*)alloc((size_t)2048 * 1024 * 2);
  ushort_t* in_ln = (ushort_t*)alloc((size_t)16384 * 768 * 2);
  ushort_t* Wqt   = (ushort_t*)alloc((size_t)1024 * 1024 * 2);
  ushort_t* Wkt   = (ushort_t*)alloc((size_t)1024 * 768 * 2);
  ushort_t* Wvt   = (ushort_t*)alloc((size_t)1024 * 768 * 2);
  // phase 2: attention partials (alias phase 1)
  off = base2;
  float* ctxp = (float*)alloc((size_t)NSPLIT * NROWS * DH * 4);
  float* mlp  = (float*)alloc((size_t)NSPLIT * NROWS * 2 * 4);

  ln_kernel<1024><<<2048, 256, 0, stream>>>(hs, ln1g, ln1b, hs_ln);
  ln_kernel<768><<<16384, 256, 0, stream>>>(inp, ln2g, ln2b, in_ln);
  wtrans_kernel<<<dim3(32, 32), 256, 0, stream>>>(Wq, Wqt, 1024, 1024);
  wtrans_kernel<<<dim3(32, 24), 256, 0, stream>>>(Wk, Wkt, 768, 1024);
  wtrans_kernel<<<dim3(32, 24), 256, 0, stream>>>(Wv, Wvt, 768, 1024);
  gemm_kernel<false><<<dim3(16, 8),  256, 0, stream>>>(hs_ln, Wqt, bq, Qm, 2048, 1024);
  gemm_kernel<false><<<dim3(128, 8), 256, 0, stream>>>(in_ln, Wkt, bk, Km, 16384, 768);
  gemm_kernel<true ><<<dim3(128, 8), 256, 0, stream>>>(in_ln, Wvt, bv, Vt, 16384, 768);
  attn_kernel<<<256, 512, 0, stream>>>(Qm, Km, Vt, ctxp, mlp);
  combine_kernel<<<NROWS / 4, 256, 0, stream>>>(ctxp, mlp, (float*)d_out);
}